// Round 2
// baseline (297.230 us; speedup 1.0000x reference)
//
#include <hip/hip_runtime.h>
#include <hip/hip_bf16.h>

// SparseEmbedding: out[b,d] = sum_n vals[b,n] * kernel[idx[b,n], d] + bias[d]
// B=4096, NNZ=32, V=1e6, D=64, all fp32 (idx int32).
//
// R1 restructure: ONE WAVE PER ROW, lane = dim.
//  - row forced wave-uniform (readfirstlane) so idx/vals become s_load
//    (scalar path): all 32 indices arrive in ~1 miss, free broadcast.
//  - each gather is global_load_dword with uniform row base: 64 lanes x 4B
//    = full 256B kernel row per instruction; 32 independent gathers/wave.
//  - 4096 waves = 16 waves/CU (vs 4 in R0) -> 4x TLP, low VGPR (~40).

#define B_BATCH 4096
#define NNZ 32
#define DIM 64

__global__ __launch_bounds__(256) void sparse_embed_kernel(
    const int* __restrict__ idx,
    const float* __restrict__ vals,
    const float* __restrict__ kern,
    const float* __restrict__ bias,
    float* __restrict__ out)
{
    const int lane = threadIdx.x & 63;          // dim index
    int row = (blockIdx.x << 2) + (threadIdx.x >> 6);   // 4 waves/block
    row = __builtin_amdgcn_readfirstlane(row);  // force SGPR -> scalar loads

    const int*   irow = idx  + row * NNZ;
    const float* vrow = vals + row * NNZ;

    // Wave-uniform index/value fetch (scalar path).
    int   ids[NNZ];
    float vs[NNZ];
    #pragma unroll
    for (int n = 0; n < NNZ; ++n) {
        ids[n] = irow[n];
        vs[n]  = vrow[n];
    }

    float acc = bias[lane];

    // 32 independent dword gathers; each covers one full 256B row per wave.
    #pragma unroll
    for (int n = 0; n < NNZ; ++n) {
        const float k = kern[(size_t)ids[n] * DIM + lane];
        acc = fmaf(vs[n], k, acc);
    }

    out[row * DIM + lane] = acc;
}

extern "C" void kernel_launch(void* const* d_in, const int* in_sizes, int n_in,
                              void* d_out, int out_size, void* d_ws, size_t ws_size,
                              hipStream_t stream) {
    const int*   idx  = (const int*)  d_in[0];
    const float* vals = (const float*)d_in[1];
    const float* kern = (const float*)d_in[2];
    const float* bias = (const float*)d_in[3];
    float* out = (float*)d_out;

    const int threads = 256;                    // 4 waves = 4 rows per block
    const int blocks  = B_BATCH / 4;            // 1024 blocks

    sparse_embed_kernel<<<blocks, threads, 0, stream>>>(idx, vals, kern, bias, out);
}